// Round 4
// baseline (224.594 us; speedup 1.0000x reference)
//
#include <hip/hip_runtime.h>

#define N_NODES 100000
#define N_EDGES 1600000
#define D 64
#define NB 391            // row buckets of 256 rows
#define PBLK 512          // partition blocks
#define CHUNK ((N_EDGES + PBLK - 1) / PBLK)   // 3125 edges per partition block
#define FLATN (NB * PBLK) // 200192 count-matrix entries
#define SB1 ((FLATN + 255) / 256)             // 782 scan blocks (<1024)

__device__ __forceinline__ unsigned short f2b(float f) {
    unsigned u = __float_as_uint(f);
    u += 0x7FFF + ((u >> 16) & 1);            // round-to-nearest-even
    return (unsigned short)(u >> 16);
}
__device__ __forceinline__ float b2f(unsigned short v) {
    return __uint_as_float(((unsigned)v) << 16);
}

// ---- pass 1: per-(block,bucket) edge counts via LDS histogram ----
__global__ void count_kernel(const int* __restrict__ ei, int* __restrict__ counts) {
    __shared__ int h[NB];
    for (int i = threadIdx.x; i < NB; i += 256) h[i] = 0;
    __syncthreads();
    int s = blockIdx.x * CHUNK;
    int e = min(s + CHUNK, N_EDGES);
    for (int i = s + (int)threadIdx.x; i < e; i += 256) {
        int r = ei[i], c = ei[N_EDGES + i];
        if (r != c) atomicAdd(&h[r >> 8], 1);
    }
    __syncthreads();
    for (int i = threadIdx.x; i < NB; i += 256) counts[i * PBLK + blockIdx.x] = h[i];
}

// ---- pass 2a: per-block exclusive scan (in place) ----
__global__ void scan1_kernel(int* __restrict__ a, int* __restrict__ blocksums) {
    __shared__ int s[256];
    int i = blockIdx.x * 256 + threadIdx.x;
    int v = (i < FLATN) ? a[i] : 0;
    s[threadIdx.x] = v;
    __syncthreads();
    for (int off = 1; off < 256; off <<= 1) {
        int t = (threadIdx.x >= off) ? s[threadIdx.x - off] : 0;
        __syncthreads();
        s[threadIdx.x] += t;
        __syncthreads();
    }
    if (i < FLATN) a[i] = s[threadIdx.x] - v;
    if (threadIdx.x == 255) blocksums[blockIdx.x] = s[255];
}

// ---- pass 2b: scan block sums (SB1=782 <= 1024) ----
__global__ void scan2_kernel(int* __restrict__ blocksums, int* __restrict__ rowptr) {
    __shared__ int s[1024];
    int t = threadIdx.x;
    int v = (t < SB1) ? blocksums[t] : 0;
    s[t] = v;
    __syncthreads();
    for (int off = 1; off < 1024; off <<= 1) {
        int u = (t >= off) ? s[t - off] : 0;
        __syncthreads();
        s[t] += u;
        __syncthreads();
    }
    if (t < SB1) blocksums[t] = s[t] - v;
    if (t == SB1 - 1) rowptr[N_NODES] = s[t];  // total non-self edges
}

// ---- pass 2c: add back block offsets ----
__global__ void scan3_kernel(int* __restrict__ a, const int* __restrict__ blocksums) {
    int i = blockIdx.x * blockDim.x + threadIdx.x;
    if (i < FLATN) a[i] += blocksums[i >> 8];
}

// ---- pass 3: partition scatter into per-(block,bucket) contiguous runs ----
__global__ void scatter_part_kernel(const int* __restrict__ ei, const int* __restrict__ offsets,
                                    int* __restrict__ epack) {
    __shared__ int cur[NB];
    for (int i = threadIdx.x; i < NB; i += 256) cur[i] = offsets[i * PBLK + blockIdx.x];
    __syncthreads();
    int s = blockIdx.x * CHUNK;
    int e = min(s + CHUNK, N_EDGES);
    for (int i = s + (int)threadIdx.x; i < e; i += 256) {
        int r = ei[i], c = ei[N_EDGES + i];
        if (r != c) {
            int p = atomicAdd(&cur[r >> 8], 1);
            epack[p] = ((r & 255) << 17) | c;   // c < 2^17
        }
    }
}

// ---- pass 4: per-bucket LDS counting sort by row; emit rowptr, dinv, sortedCol ----
__global__ void rowsort_kernel(const int* __restrict__ offsets, const int* __restrict__ total_src,
                               const int* __restrict__ epack, int* __restrict__ rowptr,
                               float* __restrict__ dinv, int* __restrict__ sortedCol) {
    __shared__ int h[256];
    __shared__ int sc[256];
    __shared__ int cur[256];
    int b = blockIdx.x;
    int t = threadIdx.x;
    int base = offsets[b * PBLK];
    int end = (b + 1 < NB) ? offsets[(b + 1) * PBLK] : total_src[N_NODES];
    h[t] = 0;
    __syncthreads();
    for (int i = base + t; i < end; i += 256) atomicAdd(&h[epack[i] >> 17], 1);
    __syncthreads();
    int v = h[t];
    sc[t] = v;
    __syncthreads();
    for (int off = 1; off < 256; off <<= 1) {
        int u = (t >= off) ? sc[t - off] : 0;
        __syncthreads();
        sc[t] += u;
        __syncthreads();
    }
    int excl = sc[t] - v;
    int row = b * 256 + t;
    if (row < N_NODES) {
        rowptr[row] = base + excl;
        dinv[row] = rsqrtf((float)(1 + v));
    }
    cur[t] = base + excl;
    __syncthreads();
    for (int i = base + t; i < end; i += 256) {
        int p = epack[i];
        int pos = atomicAdd(&cur[p >> 17], 1);
        sortedCol[pos] = p & 0x1FFFF;
    }
}

// ---- pass 5: xs[i][d] = bf16(x[i][d] * dinv[i]) ----
__global__ void convert_kernel(const float* __restrict__ x, const float* __restrict__ dinv,
                               unsigned short* __restrict__ xs) {
    int i = blockIdx.x * blockDim.x + threadIdx.x;   // over N*D/4
    if (i >= N_NODES * D / 4) return;
    const float4* x4 = (const float4*)x;
    float4 v = x4[i];
    float di = dinv[(i * 4) >> 6];
    ushort4 o;
    o.x = f2b(v.x * di);
    o.y = f2b(v.y * di);
    o.z = f2b(v.z * di);
    o.w = f2b(v.w * di);
    ((ushort4*)xs)[i] = o;
}

// ---- pass 6: gather. One wave per row, lane d = feature d. xs pre-scaled. ----
__global__ void gather_kernel(const unsigned short* __restrict__ xs, const float* __restrict__ dinv,
                              const int* __restrict__ rowptr, const int* __restrict__ sortedCol,
                              float* __restrict__ out) {
    int t = blockIdx.x * blockDim.x + threadIdx.x;
    int r = t >> 6;
    int d = t & 63;
    if (r >= N_NODES) return;
    int start = rowptr[r];
    int end = rowptr[r + 1];
    float dr = dinv[r];
    float acc = b2f(xs[r * D + d]);              // self-loop term (xs already has dr)
    for (int j = start; j < end; j += 64) {
        int idx = j + d;
        int cj = 0;
        if (idx < end) cj = sortedCol[idx];
        int n = min(64, end - j);
        for (int k = 0; k < n; k++) {
            int c = __shfl(cj, k);
            acc += b2f(xs[c * D + d]);
        }
    }
    out[r * D + d] = dr * acc;
}

extern "C" void kernel_launch(void* const* d_in, const int* in_sizes, int n_in,
                              void* d_out, int out_size, void* d_ws, size_t ws_size,
                              hipStream_t stream) {
    const float* x = (const float*)d_in[0];
    const int* ei = (const int*)d_in[1];
    float* out = (float*)d_out;

    // workspace layout (~28 MB)
    int* offsets = (int*)d_ws;                        // [FLATN]
    int* blocksums = offsets + FLATN;                 // [1024]
    int* rowptr = blocksums + 1024;                   // [N_NODES+1]
    float* dinv = (float*)(rowptr + N_NODES + 1);     // [N_NODES]
    int* epack = (int*)(dinv + N_NODES);              // [N_EDGES]
    int* sortedCol = epack + N_EDGES;                 // [N_EDGES]
    unsigned short* xs = (unsigned short*)(sortedCol + N_EDGES); // [N_NODES*D]

    count_kernel<<<PBLK, 256, 0, stream>>>(ei, offsets);
    scan1_kernel<<<SB1, 256, 0, stream>>>(offsets, blocksums);
    scan2_kernel<<<1, 1024, 0, stream>>>(blocksums, rowptr);
    scan3_kernel<<<(FLATN + 255) / 256, 256, 0, stream>>>(offsets, blocksums);
    scatter_part_kernel<<<PBLK, 256, 0, stream>>>(ei, offsets, epack);
    rowsort_kernel<<<NB, 256, 0, stream>>>(offsets, rowptr, epack, rowptr, dinv, sortedCol);
    convert_kernel<<<(N_NODES * D / 4 + 255) / 256, 256, 0, stream>>>(x, dinv, xs);
    gather_kernel<<<(N_NODES * D + 255) / 256, 256, 0, stream>>>(xs, dinv, rowptr, sortedCol, out);
}